// Round 4
// baseline (459.181 us; speedup 1.0000x reference)
//
#include <hip/hip_runtime.h>
#include <hip/hip_bf16.h>
#include <hip/hip_fp16.h>

#define DEV __device__ __forceinline__

typedef __attribute__((ext_vector_type(8))) short short8;
typedef __attribute__((ext_vector_type(4))) float floatx4;

DEV float bf2f(unsigned short b) { return __uint_as_float(((unsigned)b) << 16); }

DEV unsigned short f2bf(float f) {  // RNE float->bf16 (finite inputs only)
  unsigned u = __float_as_uint(f);
  u += 0x7FFFu + ((u >> 16) & 1u);
  return (unsigned short)(u >> 16);
}

DEV short bsq(short x) {  // bf16 bits -> (x*x) as bf16 bits
  float f = __uint_as_float(((unsigned)(unsigned short)x) << 16);
  return (short)f2bf(f * f);
}

DEV void async_ld16(const void* g, void* l) {
  __builtin_amdgcn_global_load_lds(
      (const __attribute__((address_space(1))) unsigned int*)g,
      (__attribute__((address_space(3))) unsigned int*)l, 16, 0, 0);
}

// Runtime dtype probe (safety net): 1 if float tensors are bf16-packed, 0 if fp32.
DEV int detect_bf16(const void* x_mean) {
  const unsigned* w = (const unsigned*)x_mean;
  unsigned v = w[threadIdx.x & 63];
  unsigned ex = (v >> 7) & 0xFFu;
  int vote = (ex >= 100u && ex <= 144u) ? 1 : 0;
  unsigned long long b = __ballot(vote);
  return __popcll(b) >= 48 ? 1 : 0;
}

DEV float load_elem(const void* p, int isbf, size_t i) {
  return isbf ? bf2f(((const unsigned short*)p)[i]) : ((const float*)p)[i];
}

// Load 8 consecutive elements (either dtype) -> 8 bf16 shorts into LDS.
DEV void stage8(const void* src, int isbf, size_t idx, unsigned short* dst) {
  if (isbf) {
    *(short8*)dst = *(const short8*)((const unsigned short*)src + idx);
  } else {
    const float* f = (const float*)src + idx;
    float4 a = *(const float4*)f;
    float4 b = *(const float4*)(f + 4);
    short8 o;
    o[0] = (short)f2bf(a.x); o[1] = (short)f2bf(a.y);
    o[2] = (short)f2bf(a.z); o[3] = (short)f2bf(a.w);
    o[4] = (short)f2bf(b.x); o[5] = (short)f2bf(b.y);
    o[6] = (short)f2bf(b.z); o[7] = (short)f2bf(b.w);
    *(short8*)dst = o;
  }
}

// ---------- convert-staging 128x128 NT GEMM: C = scale*(A@B^T + bias), K=256 ----------
// A: [M,256], B: [N,256] in either dtype. bias_mode: -1 none, 0 bias[col], 1 bias[row]
template <bool F32_OUT>
DEV void gemm_cvt_core(const void* A, int a_bf, const void* B, int b_bf,
                       const void* bias, int bias_bf,
                       void* __restrict__ Cv, size_t ldc,
                       size_t i0, size_t j0, float scale, int bias_mode) {
  __shared__ __align__(16) unsigned short As[128 * 32];
  __shared__ __align__(16) unsigned short Bs[128 * 32];
  const int t = threadIdx.x;
  const int lane = t & 63, wave = t >> 6;
  const int wr = wave >> 1, wc = wave & 1;
  const int q = lane >> 4, m = lane & 15;
  floatx4 acc[4][4] = {};
  for (int k0 = 0; k0 < 256; k0 += 32) {
#pragma unroll
    for (int it = 0; it < 2; ++it) {
      int e = it * 2048 + t * 8;
      int row = e >> 5, col = e & 31;
      stage8(A, a_bf, (i0 + row) * (size_t)256 + k0 + col, &As[e]);
      stage8(B, b_bf, (j0 + row) * (size_t)256 + k0 + col, &Bs[e]);
    }
    __syncthreads();
    short8 af[4], bfr[4];
#pragma unroll
    for (int r = 0; r < 4; ++r)
      af[r] = *(const short8*)&As[(wr * 64 + r * 16 + m) * 32 + q * 8];
#pragma unroll
    for (int c = 0; c < 4; ++c)
      bfr[c] = *(const short8*)&Bs[(wc * 64 + c * 16 + m) * 32 + q * 8];
#pragma unroll
    for (int r = 0; r < 4; ++r)
#pragma unroll
      for (int c = 0; c < 4; ++c)
        acc[r][c] = __builtin_amdgcn_mfma_f32_16x16x32_bf16(af[r], bfr[c], acc[r][c], 0, 0, 0);
    __syncthreads();
  }
#pragma unroll
  for (int r = 0; r < 4; ++r) {
#pragma unroll
    for (int c = 0; c < 4; ++c) {
      size_t col = j0 + wc * 64 + c * 16 + m;
      float bcol = (bias_mode == 0) ? load_elem(bias, bias_bf, col) : 0.f;
#pragma unroll
      for (int g = 0; g < 4; ++g) {
        size_t row = i0 + wr * 64 + r * 16 + q * 4 + g;
        float val = acc[r][c][g] + bcol;
        if (bias_mode == 1) val += load_elem(bias, bias_bf, row);
        val *= scale;
        if (F32_OUT)
          ((float*)Cv)[row * ldc + col] = val;
        else
          ((unsigned short*)Cv)[row * ldc + col] = f2bf(val);
      }
    }
  }
}

// ---------- K1: four input projections (bf16 outputs to ws) ----------
struct ProjArgs {
  const void* A[4];
  const void* B[4];
  const void* bias[4];
  unsigned short* C[4];
  unsigned long ldc[4];
  float scale[4];
  int bias_row[4];
  const void* xdet;
};

__global__ __launch_bounds__(256) void proj_kernel(ProjArgs p) {
  int isbf = detect_bf16(p.xdet);
  int z = blockIdx.z;
  size_t i0, j0;
  if (z < 2) { i0 = (size_t)blockIdx.x * 128; j0 = (size_t)blockIdx.y * 128; }
  else       { i0 = (size_t)blockIdx.y * 128; j0 = (size_t)blockIdx.x * 128; }
  gemm_cvt_core<false>(p.A[z], isbf, p.B[z], isbf, p.bias[z], isbf, p.C[z],
                       p.ldc[z], i0, j0, p.scale[z], p.bias_row[z]);
}

// ---------- K2: S = q'@k^T (0.125 and bq folded into q'), fp16 out ----------
__global__ __launch_bounds__(256) void qk_kernel(const unsigned short* __restrict__ qb,
                                                 const unsigned short* __restrict__ kb,
                                                 unsigned short* __restrict__ S) {
  __shared__ __align__(16) unsigned short As[128 * 32];
  __shared__ __align__(16) unsigned short Bs[128 * 32];
  const int t = threadIdx.x;
  const int lane = t & 63, wave = t >> 6;
  const int wr = wave >> 1, wc = wave & 1;
  const int q = lane >> 4, m = lane & 15;
  const size_t i0 = (size_t)blockIdx.x * 128, j0 = (size_t)blockIdx.y * 128;
  floatx4 acc[4][4] = {};
  for (int k0 = 0; k0 < 256; k0 += 32) {
#pragma unroll
    for (int it = 0; it < 2; ++it) {
      int e = it * 2048 + t * 8;
      int row = e >> 5, col = e & 31;
      async_ld16(&qb[(i0 + row) * 256 + k0 + col], &As[e]);
      async_ld16(&kb[(j0 + row) * 256 + k0 + col], &Bs[e]);
    }
    __syncthreads();
    short8 af[4], bfr[4];
#pragma unroll
    for (int r = 0; r < 4; ++r)
      af[r] = *(const short8*)&As[(wr * 64 + r * 16 + m) * 32 + q * 8];
#pragma unroll
    for (int c = 0; c < 4; ++c)
      bfr[c] = *(const short8*)&Bs[(wc * 64 + c * 16 + m) * 32 + q * 8];
#pragma unroll
    for (int r = 0; r < 4; ++r)
#pragma unroll
      for (int c = 0; c < 4; ++c)
        acc[r][c] = __builtin_amdgcn_mfma_f32_16x16x32_bf16(af[r], bfr[c], acc[r][c], 0, 0, 0);
    __syncthreads();
  }
#pragma unroll
  for (int r = 0; r < 4; ++r)
#pragma unroll
    for (int c = 0; c < 4; ++c) {
      size_t col = j0 + wc * 64 + c * 16 + m;
#pragma unroll
      for (int g = 0; g < 4; ++g) {
        size_t row = i0 + wr * 64 + r * 16 + q * 4 + g;
        S[row * 8192 + col] = __half_as_ushort(__float2half_rn(acc[r][c][g]));
      }
    }
}

// ---------- K3: row softmax, fp16 in -> bf16 out, in place ----------
__global__ __launch_bounds__(256) void softmax_kernel(unsigned short* __restrict__ SA) {
  unsigned short* p = SA + (size_t)blockIdx.x * 8192;
  const int t = threadIdx.x;
  const int lane = t & 63, wave = t >> 6;
  float v[32];
#pragma unroll
  for (int c = 0; c < 4; ++c) {
    short8 raw = *(const short8*)(p + c * 2048 + t * 8);
#pragma unroll
    for (int j = 0; j < 8; ++j)
      v[c * 8 + j] = __half2float(__ushort_as_half((unsigned short)raw[j]));
  }
  float mx = -3.0e38f;
#pragma unroll
  for (int i = 0; i < 32; ++i) mx = fmaxf(mx, v[i]);
#pragma unroll
  for (int o = 32; o > 0; o >>= 1) mx = fmaxf(mx, __shfl_down(mx, o));
  __shared__ float sred[4];
  if (lane == 0) sred[wave] = mx;
  __syncthreads();
  mx = fmaxf(fmaxf(sred[0], sred[1]), fmaxf(sred[2], sred[3]));
  float s = 0.f;
#pragma unroll
  for (int i = 0; i < 32; ++i) { v[i] = __expf(v[i] - mx); s += v[i]; }
#pragma unroll
  for (int o = 32; o > 0; o >>= 1) s += __shfl_down(s, o);
  __shared__ float sred2[4];
  if (lane == 0) sred2[wave] = s;
  __syncthreads();
  s = sred2[0] + sred2[1] + sred2[2] + sred2[3];
  float inv = 1.f / s;
#pragma unroll
  for (int c = 0; c < 4; ++c) {
    short8 o8;
#pragma unroll
    for (int j = 0; j < 8; ++j) o8[j] = (short)f2bf(v[c * 8 + j] * inv);
    *(short8*)(p + c * 2048 + t * 8) = o8;
  }
}

// ---------- zero accumulators (runs after qk: ot_f32 aliases dead qb/kb) ----------
__global__ __launch_bounds__(256) void zero_kernel(float* __restrict__ a,
                                                   float* __restrict__ b) {
  size_t i = ((size_t)blockIdx.x * 256 + threadIdx.x) * 4;
  float4 z = {0.f, 0.f, 0.f, 0.f};
  *(float4*)(a + i) = z;
  *(float4*)(b + i) = z;
}

// ---------- K4: split-K fused  ot_f32 += attn@v,  out_var += attn^2@v_var ----------
// attn: [8192,8192] bf16; vT/vvT: [256,8192] bf16. 128x128 tile, K-slice 1024.
// grid (64, 2, 8) = 1024 blocks; fp32 accumulation via HW atomic fadd.
__global__ __launch_bounds__(256) void av_kernel(const unsigned short* __restrict__ attn,
                                                 const unsigned short* __restrict__ vT,
                                                 const unsigned short* __restrict__ vvT,
                                                 float* __restrict__ ot_f32,
                                                 float* __restrict__ out_var) {
  __shared__ __align__(16) unsigned short As[128 * 32];
  __shared__ __align__(16) unsigned short B1[128 * 32];
  __shared__ __align__(16) unsigned short B2[128 * 32];
  const int t = threadIdx.x;
  const int lane = t & 63, wave = t >> 6;
  const int wr = wave >> 1, wc = wave & 1;
  const int q = lane >> 4, m = lane & 15;
  const size_t i0 = (size_t)blockIdx.x * 128, j0 = (size_t)blockIdx.y * 128;
  const int kbase = blockIdx.z * 1024;
  floatx4 accm[4][4] = {}, accv[4][4] = {};
  for (int k0 = kbase; k0 < kbase + 1024; k0 += 32) {
#pragma unroll
    for (int it = 0; it < 2; ++it) {
      int e = it * 2048 + t * 8;
      int row = e >> 5, col = e & 31;
      async_ld16(&attn[(i0 + row) * 8192 + k0 + col], &As[e]);
      async_ld16(&vT[(j0 + row) * 8192 + k0 + col], &B1[e]);
      async_ld16(&vvT[(j0 + row) * 8192 + k0 + col], &B2[e]);
    }
    __syncthreads();
    short8 af[4], aq[4], b1[4], b2[4];
#pragma unroll
    for (int r = 0; r < 4; ++r) {
      af[r] = *(const short8*)&As[(wr * 64 + r * 16 + m) * 32 + q * 8];
#pragma unroll
      for (int j = 0; j < 8; ++j) aq[r][j] = bsq(af[r][j]);
    }
#pragma unroll
    for (int c = 0; c < 4; ++c) {
      b1[c] = *(const short8*)&B1[(wc * 64 + c * 16 + m) * 32 + q * 8];
      b2[c] = *(const short8*)&B2[(wc * 64 + c * 16 + m) * 32 + q * 8];
    }
#pragma unroll
    for (int r = 0; r < 4; ++r)
#pragma unroll
      for (int c = 0; c < 4; ++c) {
        accm[r][c] = __builtin_amdgcn_mfma_f32_16x16x32_bf16(af[r], b1[c], accm[r][c], 0, 0, 0);
        accv[r][c] = __builtin_amdgcn_mfma_f32_16x16x32_bf16(aq[r], b2[c], accv[r][c], 0, 0, 0);
      }
    __syncthreads();
  }
#pragma unroll
  for (int r = 0; r < 4; ++r)
#pragma unroll
    for (int c = 0; c < 4; ++c) {
      size_t col = j0 + wc * 64 + c * 16 + m;
#pragma unroll
      for (int g = 0; g < 4; ++g) {
        size_t row = i0 + wr * 64 + r * 16 + q * 4 + g;
        unsafeAtomicAdd(&ot_f32[row * 256 + col], accm[r][c][g]);
        unsafeAtomicAdd(&out_var[row * 256 + col], accv[r][c][g]);
      }
    }
}

// ---------- K5: out_mean(fp32) = ot_f32 @ Wo^T + bo ----------
__global__ __launch_bounds__(256) void final_kernel(const float* __restrict__ ot,
                                                    const void* Wo, const void* bo,
                                                    const void* xdet,
                                                    float* __restrict__ Cm) {
  int isbf = detect_bf16(xdet);
  gemm_cvt_core<true>(ot, 0, Wo, isbf, bo, isbf, Cm, 256,
                      (size_t)blockIdx.x * 128, (size_t)blockIdx.y * 128, 1.f, 0);
}

extern "C" void kernel_launch(void* const* d_in, const int* in_sizes, int n_in,
                              void* d_out, int out_size, void* d_ws, size_t ws_size,
                              hipStream_t stream) {
  const void* x_mean = d_in[0];
  const void* x_var  = d_in[1];
  // d_in[2] edge_index, d_in[3] edge_timestamps: unused by the reference
  const void* Wq   = d_in[4];
  const void* bq   = d_in[5];
  const void* Wk   = d_in[6];
  const void* bk   = d_in[7];
  const void* Wv   = d_in[8];
  const void* bv   = d_in[9];
  const void* Wo   = d_in[10];
  const void* bo   = d_in[11];
  const void* Wvar = d_in[12];
  const void* bvar = d_in[13];
  float* out = (float*)d_out;  // [out_mean (8192*256) | out_var (8192*256)] fp32

  const size_t NE_S = 67108864;  // 8192*8192
  const size_t NE_P = 2097152;   // 8192*256
  if (ws_size < (NE_S + 5 * NE_P) * 2) return;  // ~155 MB scratch (unchanged)
  unsigned short* w   = (unsigned short*)d_ws;
  unsigned short* S   = w;              // fp16 logits, then bf16 attn in place
  unsigned short* qb  = w + NE_S;       // q*0.125 (+bq), bf16 [8192,256]
  unsigned short* kb  = qb + NE_P;      // k, bf16 [8192,256]
  unsigned short* vT  = kb + NE_P;      // v^T, bf16 [256,8192]
  unsigned short* vvT = vT + NE_P;      // v_var^T, bf16 [256,8192]
  // fp32 mean accumulator aliases qb+kb (dead after qk_kernel): 8 MB exactly
  float* ot_f32 = (float*)qb;

  ProjArgs p;
  p.A[0] = x_mean; p.B[0] = Wq;     p.bias[0] = bq;   p.C[0] = qb;  p.ldc[0] = 256;  p.scale[0] = 0.125f; p.bias_row[0] = 0;
  p.A[1] = x_mean; p.B[1] = Wk;     p.bias[1] = bk;   p.C[1] = kb;  p.ldc[1] = 256;  p.scale[1] = 1.f;    p.bias_row[1] = 0;
  p.A[2] = Wv;     p.B[2] = x_mean; p.bias[2] = bv;   p.C[2] = vT;  p.ldc[2] = 8192; p.scale[2] = 1.f;    p.bias_row[2] = 1;
  p.A[3] = Wvar;   p.B[3] = x_var;  p.bias[3] = bvar; p.C[3] = vvT; p.ldc[3] = 8192; p.scale[3] = 1.f;    p.bias_row[3] = 1;
  p.xdet = x_mean;

  proj_kernel<<<dim3(64, 2, 4), 256, 0, stream>>>(p);
  qk_kernel<<<dim3(64, 64), 256, 0, stream>>>(qb, kb, S);
  // zero AFTER qk (ot_f32 overwrites qb/kb), BEFORE av
  zero_kernel<<<dim3(2048), 256, 0, stream>>>(ot_f32, out + NE_P);
  softmax_kernel<<<dim3(8192), 256, 0, stream>>>(S);
  av_kernel<<<dim3(64, 2, 8), 256, 0, stream>>>(S, vT, vvT, ot_f32, out + NE_P);
  final_kernel<<<dim3(64, 2), 256, 0, stream>>>(ot_f32, Wo, bo, x_mean, out);
}

// Round 5
// 434.220 us; speedup vs baseline: 1.0575x; 1.0575x over previous
//
#include <hip/hip_runtime.h>
#include <hip/hip_bf16.h>
#include <hip/hip_fp16.h>

#define DEV __device__ __forceinline__

typedef __attribute__((ext_vector_type(8))) short short8;
typedef __attribute__((ext_vector_type(4))) float floatx4;

DEV float bf2f(unsigned short b) { return __uint_as_float(((unsigned)b) << 16); }

DEV unsigned short f2bf(float f) {  // RNE float->bf16 (finite inputs only)
  unsigned u = __float_as_uint(f);
  u += 0x7FFFu + ((u >> 16) & 1u);
  return (unsigned short)(u >> 16);
}

DEV short bsq(short x) {  // bf16 bits -> (x*x) as bf16 bits
  float f = __uint_as_float(((unsigned)(unsigned short)x) << 16);
  return (short)f2bf(f * f);
}

DEV void async_ld16(const void* g, void* l) {
  __builtin_amdgcn_global_load_lds(
      (const __attribute__((address_space(1))) unsigned int*)g,
      (__attribute__((address_space(3))) unsigned int*)l, 16, 0, 0);
}

// Runtime dtype probe (safety net): 1 if float tensors are bf16-packed, 0 if fp32.
DEV int detect_bf16(const void* x_mean) {
  const unsigned* w = (const unsigned*)x_mean;
  unsigned v = w[threadIdx.x & 63];
  unsigned ex = (v >> 7) & 0xFFu;
  int vote = (ex >= 100u && ex <= 144u) ? 1 : 0;
  unsigned long long b = __ballot(vote);
  return __popcll(b) >= 48 ? 1 : 0;
}

DEV float load_elem(const void* p, int isbf, size_t i) {
  return isbf ? bf2f(((const unsigned short*)p)[i]) : ((const float*)p)[i];
}

// Load 8 consecutive elements (either dtype) -> 8 bf16 shorts into LDS.
DEV void stage8(const void* src, int isbf, size_t idx, unsigned short* dst) {
  if (isbf) {
    *(short8*)dst = *(const short8*)((const unsigned short*)src + idx);
  } else {
    const float* f = (const float*)src + idx;
    float4 a = *(const float4*)f;
    float4 b = *(const float4*)(f + 4);
    short8 o;
    o[0] = (short)f2bf(a.x); o[1] = (short)f2bf(a.y);
    o[2] = (short)f2bf(a.z); o[3] = (short)f2bf(a.w);
    o[4] = (short)f2bf(b.x); o[5] = (short)f2bf(b.y);
    o[6] = (short)f2bf(b.z); o[7] = (short)f2bf(b.w);
    *(short8*)dst = o;
  }
}

// ---------- convert-staging 128x128 NT GEMM: C = scale*(A@B^T + bias), K=256 ----------
template <bool F32_OUT>
DEV void gemm_cvt_core(const void* A, int a_bf, const void* B, int b_bf,
                       const void* bias, int bias_bf,
                       void* __restrict__ Cv, size_t ldc,
                       size_t i0, size_t j0, float scale, int bias_mode) {
  __shared__ __align__(16) unsigned short As[128 * 32];
  __shared__ __align__(16) unsigned short Bs[128 * 32];
  const int t = threadIdx.x;
  const int lane = t & 63, wave = t >> 6;
  const int wr = wave >> 1, wc = wave & 1;
  const int q = lane >> 4, m = lane & 15;
  floatx4 acc[4][4] = {};
  for (int k0 = 0; k0 < 256; k0 += 32) {
#pragma unroll
    for (int it = 0; it < 2; ++it) {
      int e = it * 2048 + t * 8;
      int row = e >> 5, col = e & 31;
      stage8(A, a_bf, (i0 + row) * (size_t)256 + k0 + col, &As[e]);
      stage8(B, b_bf, (j0 + row) * (size_t)256 + k0 + col, &Bs[e]);
    }
    __syncthreads();
    short8 af[4], bfr[4];
#pragma unroll
    for (int r = 0; r < 4; ++r)
      af[r] = *(const short8*)&As[(wr * 64 + r * 16 + m) * 32 + q * 8];
#pragma unroll
    for (int c = 0; c < 4; ++c)
      bfr[c] = *(const short8*)&Bs[(wc * 64 + c * 16 + m) * 32 + q * 8];
#pragma unroll
    for (int r = 0; r < 4; ++r)
#pragma unroll
      for (int c = 0; c < 4; ++c)
        acc[r][c] = __builtin_amdgcn_mfma_f32_16x16x32_bf16(af[r], bfr[c], acc[r][c], 0, 0, 0);
    __syncthreads();
  }
#pragma unroll
  for (int r = 0; r < 4; ++r) {
#pragma unroll
    for (int c = 0; c < 4; ++c) {
      size_t col = j0 + wc * 64 + c * 16 + m;
      float bcol = (bias_mode == 0) ? load_elem(bias, bias_bf, col) : 0.f;
#pragma unroll
      for (int g = 0; g < 4; ++g) {
        size_t row = i0 + wr * 64 + r * 16 + q * 4 + g;
        float val = acc[r][c][g] + bcol;
        if (bias_mode == 1) val += load_elem(bias, bias_bf, row);
        val *= scale;
        if (F32_OUT)
          ((float*)Cv)[row * ldc + col] = val;
        else
          ((unsigned short*)Cv)[row * ldc + col] = f2bf(val);
      }
    }
  }
}

// ---------- K1: four input projections (bf16 outputs to ws) ----------
struct ProjArgs {
  const void* A[4];
  const void* B[4];
  const void* bias[4];
  unsigned short* C[4];
  unsigned long ldc[4];
  float scale[4];
  int bias_row[4];
  const void* xdet;
};

__global__ __launch_bounds__(256) void proj_kernel(ProjArgs p) {
  int isbf = detect_bf16(p.xdet);
  int z = blockIdx.z;
  size_t i0, j0;
  if (z < 2) { i0 = (size_t)blockIdx.x * 128; j0 = (size_t)blockIdx.y * 128; }
  else       { i0 = (size_t)blockIdx.y * 128; j0 = (size_t)blockIdx.x * 128; }
  gemm_cvt_core<false>(p.A[z], isbf, p.B[z], isbf, p.bias[z], isbf, p.C[z],
                       p.ldc[z], i0, j0, p.scale[z], p.bias_row[z]);
}

// ---------- K2: S = q'@k^T (0.125 and bq folded into q'), fp16 out ----------
__global__ __launch_bounds__(256) void qk_kernel(const unsigned short* __restrict__ qb,
                                                 const unsigned short* __restrict__ kb,
                                                 unsigned short* __restrict__ S) {
  __shared__ __align__(16) unsigned short As[128 * 32];
  __shared__ __align__(16) unsigned short Bs[128 * 32];
  const int t = threadIdx.x;
  const int lane = t & 63, wave = t >> 6;
  const int wr = wave >> 1, wc = wave & 1;
  const int q = lane >> 4, m = lane & 15;
  const size_t i0 = (size_t)blockIdx.x * 128, j0 = (size_t)blockIdx.y * 128;
  floatx4 acc[4][4] = {};
  for (int k0 = 0; k0 < 256; k0 += 32) {
#pragma unroll
    for (int it = 0; it < 2; ++it) {
      int e = it * 2048 + t * 8;
      int row = e >> 5, col = e & 31;
      async_ld16(&qb[(i0 + row) * 256 + k0 + col], &As[e]);
      async_ld16(&kb[(j0 + row) * 256 + k0 + col], &Bs[e]);
    }
    __syncthreads();
    short8 af[4], bfr[4];
#pragma unroll
    for (int r = 0; r < 4; ++r)
      af[r] = *(const short8*)&As[(wr * 64 + r * 16 + m) * 32 + q * 8];
#pragma unroll
    for (int c = 0; c < 4; ++c)
      bfr[c] = *(const short8*)&Bs[(wc * 64 + c * 16 + m) * 32 + q * 8];
#pragma unroll
    for (int r = 0; r < 4; ++r)
#pragma unroll
      for (int c = 0; c < 4; ++c)
        acc[r][c] = __builtin_amdgcn_mfma_f32_16x16x32_bf16(af[r], bfr[c], acc[r][c], 0, 0, 0);
    __syncthreads();
  }
#pragma unroll
  for (int r = 0; r < 4; ++r)
#pragma unroll
    for (int c = 0; c < 4; ++c) {
      size_t col = j0 + wc * 64 + c * 16 + m;
#pragma unroll
      for (int g = 0; g < 4; ++g) {
        size_t row = i0 + wr * 64 + r * 16 + q * 4 + g;
        S[row * 8192 + col] = __half_as_ushort(__float2half_rn(acc[r][c][g]));
      }
    }
}

// ---------- K3: row softmax, fp16 in -> bf16 out, in place ----------
__global__ __launch_bounds__(256) void softmax_kernel(unsigned short* __restrict__ SA) {
  unsigned short* p = SA + (size_t)blockIdx.x * 8192;
  const int t = threadIdx.x;
  const int lane = t & 63, wave = t >> 6;
  float v[32];
#pragma unroll
  for (int c = 0; c < 4; ++c) {
    short8 raw = *(const short8*)(p + c * 2048 + t * 8);
#pragma unroll
    for (int j = 0; j < 8; ++j)
      v[c * 8 + j] = __half2float(__ushort_as_half((unsigned short)raw[j]));
  }
  float mx = -3.0e38f;
#pragma unroll
  for (int i = 0; i < 32; ++i) mx = fmaxf(mx, v[i]);
#pragma unroll
  for (int o = 32; o > 0; o >>= 1) mx = fmaxf(mx, __shfl_down(mx, o));
  __shared__ float sred[4];
  if (lane == 0) sred[wave] = mx;
  __syncthreads();
  mx = fmaxf(fmaxf(sred[0], sred[1]), fmaxf(sred[2], sred[3]));
  float s = 0.f;
#pragma unroll
  for (int i = 0; i < 32; ++i) { v[i] = __expf(v[i] - mx); s += v[i]; }
#pragma unroll
  for (int o = 32; o > 0; o >>= 1) s += __shfl_down(s, o);
  __shared__ float sred2[4];
  if (lane == 0) sred2[wave] = s;
  __syncthreads();
  s = sred2[0] + sred2[1] + sred2[2] + sred2[3];
  float inv = 1.f / s;
#pragma unroll
  for (int c = 0; c < 4; ++c) {
    short8 o8;
#pragma unroll
    for (int j = 0; j < 8; ++j) o8[j] = (short)f2bf(v[c * 8 + j] * inv);
    *(short8*)(p + c * 2048 + t * 8) = o8;
  }
}

// ---------- zero accumulators (runs after qk: ot_f32 aliases dead qb/kb) ----------
__global__ __launch_bounds__(256) void zero_kernel(float* __restrict__ a,
                                                   float* __restrict__ b) {
  size_t i = ((size_t)blockIdx.x * 256 + threadIdx.x) * 4;
  float4 z = {0.f, 0.f, 0.f, 0.f};
  *(float4*)(a + i) = z;
  *(float4*)(b + i) = z;
}

// ---------- K4a/K4b: split-K GEMM  outp += (SQ? attn^2 : attn) @ BT^T ----------
// attn: [8192,8192] bf16; BT: [256,8192] bf16. 128x128 tile, K-slice 1024.
// grid (64, 2, 8) = 1024 blocks. acc[4][4] = 64 AGPR -> ~3 waves/SIMD.
template <bool SQ>
__global__ __launch_bounds__(256) void av_core(const unsigned short* __restrict__ attn,
                                               const unsigned short* __restrict__ BT,
                                               float* __restrict__ outp) {
  __shared__ __align__(16) unsigned short As[128 * 32];
  __shared__ __align__(16) unsigned short Bs[128 * 32];
  const int t = threadIdx.x;
  const int lane = t & 63, wave = t >> 6;
  const int wr = wave >> 1, wc = wave & 1;
  const int q = lane >> 4, m = lane & 15;
  const size_t i0 = (size_t)blockIdx.x * 128, j0 = (size_t)blockIdx.y * 128;
  const int kbase = blockIdx.z * 1024;
  floatx4 acc[4][4] = {};
  for (int k0 = kbase; k0 < kbase + 1024; k0 += 32) {
#pragma unroll
    for (int it = 0; it < 2; ++it) {
      int e = it * 2048 + t * 8;
      int row = e >> 5, col = e & 31;
      async_ld16(&attn[(i0 + row) * 8192 + k0 + col], &As[e]);
      async_ld16(&BT[(j0 + row) * 8192 + k0 + col], &Bs[e]);
    }
    __syncthreads();
    short8 af[4], bfr[4];
#pragma unroll
    for (int r = 0; r < 4; ++r) {
      af[r] = *(const short8*)&As[(wr * 64 + r * 16 + m) * 32 + q * 8];
      if (SQ) {
#pragma unroll
        for (int j = 0; j < 8; ++j) af[r][j] = bsq(af[r][j]);
      }
    }
#pragma unroll
    for (int c = 0; c < 4; ++c)
      bfr[c] = *(const short8*)&Bs[(wc * 64 + c * 16 + m) * 32 + q * 8];
#pragma unroll
    for (int r = 0; r < 4; ++r)
#pragma unroll
      for (int c = 0; c < 4; ++c)
        acc[r][c] = __builtin_amdgcn_mfma_f32_16x16x32_bf16(af[r], bfr[c], acc[r][c], 0, 0, 0);
    __syncthreads();
  }
#pragma unroll
  for (int r = 0; r < 4; ++r)
#pragma unroll
    for (int c = 0; c < 4; ++c) {
      size_t col = j0 + wc * 64 + c * 16 + m;
#pragma unroll
      for (int g = 0; g < 4; ++g) {
        size_t row = i0 + wr * 64 + r * 16 + q * 4 + g;
        unsafeAtomicAdd(&outp[row * 256 + col], acc[r][c][g]);
      }
    }
}

// ---------- K5: out_mean(fp32) = ot_f32 @ Wo^T + bo ----------
__global__ __launch_bounds__(256) void final_kernel(const float* __restrict__ ot,
                                                    const void* Wo, const void* bo,
                                                    const void* xdet,
                                                    float* __restrict__ Cm) {
  int isbf = detect_bf16(xdet);
  gemm_cvt_core<true>(ot, 0, Wo, isbf, bo, isbf, Cm, 256,
                      (size_t)blockIdx.x * 128, (size_t)blockIdx.y * 128, 1.f, 0);
}

extern "C" void kernel_launch(void* const* d_in, const int* in_sizes, int n_in,
                              void* d_out, int out_size, void* d_ws, size_t ws_size,
                              hipStream_t stream) {
  const void* x_mean = d_in[0];
  const void* x_var  = d_in[1];
  // d_in[2] edge_index, d_in[3] edge_timestamps: unused by the reference
  const void* Wq   = d_in[4];
  const void* bq   = d_in[5];
  const void* Wk   = d_in[6];
  const void* bk   = d_in[7];
  const void* Wv   = d_in[8];
  const void* bv   = d_in[9];
  const void* Wo   = d_in[10];
  const void* bo   = d_in[11];
  const void* Wvar = d_in[12];
  const void* bvar = d_in[13];
  float* out = (float*)d_out;  // [out_mean (8192*256) | out_var (8192*256)] fp32

  const size_t NE_S = 67108864;  // 8192*8192
  const size_t NE_P = 2097152;   // 8192*256
  if (ws_size < (NE_S + 5 * NE_P) * 2) return;  // ~155 MB scratch
  unsigned short* w   = (unsigned short*)d_ws;
  unsigned short* S   = w;              // fp16 logits, then bf16 attn in place
  unsigned short* qb  = w + NE_S;       // q*0.125 (+bq), bf16 [8192,256]
  unsigned short* kb  = qb + NE_P;      // k, bf16 [8192,256]
  unsigned short* vT  = kb + NE_P;      // v^T, bf16 [256,8192]
  unsigned short* vvT = vT + NE_P;      // v_var^T, bf16 [256,8192]
  // fp32 mean accumulator aliases qb+kb (dead after qk_kernel): 8 MB exactly
  float* ot_f32 = (float*)qb;

  ProjArgs p;
  p.A[0] = x_mean; p.B[0] = Wq;     p.bias[0] = bq;   p.C[0] = qb;  p.ldc[0] = 256;  p.scale[0] = 0.125f; p.bias_row[0] = 0;
  p.A[1] = x_mean; p.B[1] = Wk;     p.bias[1] = bk;   p.C[1] = kb;  p.ldc[1] = 256;  p.scale[1] = 1.f;    p.bias_row[1] = 0;
  p.A[2] = Wv;     p.B[2] = x_mean; p.bias[2] = bv;   p.C[2] = vT;  p.ldc[2] = 8192; p.scale[2] = 1.f;    p.bias_row[2] = 1;
  p.A[3] = Wvar;   p.B[3] = x_var;  p.bias[3] = bvar; p.C[3] = vvT; p.ldc[3] = 8192; p.scale[3] = 1.f;    p.bias_row[3] = 1;
  p.xdet = x_mean;

  proj_kernel<<<dim3(64, 2, 4), 256, 0, stream>>>(p);
  qk_kernel<<<dim3(64, 64), 256, 0, stream>>>(qb, kb, S);
  // zero AFTER qk (ot_f32 overwrites qb/kb), BEFORE av
  zero_kernel<<<dim3(2048), 256, 0, stream>>>(ot_f32, out + NE_P);
  softmax_kernel<<<dim3(8192), 256, 0, stream>>>(S);
  av_core<false><<<dim3(64, 2, 8), 256, 0, stream>>>(S, vT, ot_f32);
  av_core<true><<<dim3(64, 2, 8), 256, 0, stream>>>(S, vvT, out + NE_P);
  final_kernel<<<dim3(64, 2), 256, 0, stream>>>(ot_f32, Wo, bo, x_mean, out);
}